// Round 15
// baseline (24049.274 us; speedup 1.0000x reference)
//
#include <hip/hip_runtime.h>
#include <stdint.h>

#define NSN 20
#define NPN 8
#define NB 128
#define TT 24
#define NN 28
#define ES 100
#define EP 32
#define KHS 1280
#define KHP 768
#define NPRE 768
#define TCH 4

typedef _Float16 half_t;
typedef __attribute__((ext_vector_type(8))) _Float16 f16x8;
typedef __attribute__((ext_vector_type(4))) float f32x4;

__device__ __forceinline__ void gl16(const half_t* g, half_t* l) {
  __builtin_amdgcn_global_load_lds((const __attribute__((address_space(1))) void*)g,
                                   (__attribute__((address_space(3))) void*)l, 16, 0, 0);
}

// ---------------- graph build (edges staged in LDS) ----------------
__global__ void graph_build(const int* __restrict__ ei_s, const float* __restrict__ ew_s,
                            const int* __restrict__ ei_p, const float* __restrict__ ew_p,
                            float* __restrict__ Ms_s, float* __restrict__ Ms_p,
                            float* __restrict__ Mbig_s, float* __restrict__ Mbig_p) {
  __shared__ float Ao[NSN*NSN], Aiw[NSN*NSN], dgo[NSN], dgi[NSN];
  __shared__ float T2o[NSN*NSN], T2i[NSN*NSN];
  __shared__ float Aop[NPN*NPN], Aip[NPN*NPN], dgop[NPN], dgip[NPN];
  __shared__ int eis[2*ES]; __shared__ float ews[ES];
  __shared__ int eip[2*EP]; __shared__ float ewp[EP];
  int tid = threadIdx.x;
  for (int i = tid; i < 2*ES; i += blockDim.x) eis[i] = ei_s[i];
  for (int i = tid; i < ES; i += blockDim.x) ews[i] = ew_s[i];
  for (int i = tid; i < 2*EP; i += blockDim.x) eip[i] = ei_p[i];
  for (int i = tid; i < EP; i += blockDim.x) ewp[i] = ew_p[i];
  for (int i = tid; i < NSN*NSN; i += blockDim.x) { Ao[i] = 0.f; Aiw[i] = 0.f; }
  for (int i = tid; i < NPN*NPN; i += blockDim.x) { Aop[i] = 0.f; Aip[i] = 0.f; }
  if (tid < NSN) { dgo[tid] = 0.f; dgi[tid] = 0.f; }
  if (tid < NPN) { dgop[tid] = 0.f; dgip[tid] = 0.f; }
  __syncthreads();
  if (tid == 0) {
    for (int e = 0; e < ES; ++e) { int r = eis[e], c = eis[ES+e]; float w = ews[e]; dgo[r] += w; dgi[c] += w; }
    for (int e = 0; e < ES; ++e) { int r = eis[e], c = eis[ES+e]; Ao[c*NSN+r] += 1.f/dgo[r]; Aiw[c*NSN+r] += 1.f/dgi[r]; }
  }
  if (tid == 1) {
    for (int e = 0; e < EP; ++e) { int r = eip[e], c = eip[EP+e]; float w = ewp[e]; dgop[r] += w; dgip[c] += w; }
    for (int e = 0; e < EP; ++e) { int r = eip[e], c = eip[EP+e]; Aop[c*NPN+r] += 1.f/dgop[r]; Aip[c*NPN+r] += 1.f/dgip[r]; }
  }
  __syncthreads();
  for (int i = tid; i < NSN*NSN; i += blockDim.x) {
    int r = i / NSN, c = i % NSN;
    float so = 0.f, si = 0.f;
    for (int k = 0; k < NSN; ++k) { so += Ao[r*NSN+k]*Ao[k*NSN+c]; si += Aiw[r*NSN+k]*Aiw[k*NSN+c]; }
    float t2o = 2.f*so - (r==c ? 1.f : 0.f);
    float t2i = 2.f*si - (r==c ? 1.f : 0.f);
    T2o[i] = t2o; T2i[i] = t2i;
    Ms_s[0*NSN*NSN + i] = Ao[i];
    Ms_s[1*NSN*NSN + i] = Aiw[i];
    Ms_s[2*NSN*NSN + i] = t2o;
    Ms_s[3*NSN*NSN + i] = t2i;
  }
  for (int i = tid; i < NPN*NPN; i += blockDim.x) {
    Ms_p[0*NPN*NPN + i] = Aop[i];
    Ms_p[1*NPN*NPN + i] = Aip[i];
  }
  __syncthreads();
  for (int i = tid; i < NSN*NSN*5; i += blockDim.x) {
    int n = i / 100, s = i % 100, r = s / 5, tau = s % 5;
    float v;
    if (tau == 0) v = (n == r) ? 1.f : 0.f;
    else if (tau == 1) v = Ao[n*NSN + r];
    else if (tau == 2) v = Aiw[n*NSN + r];
    else if (tau == 3) v = T2o[n*NSN + r];
    else               v = T2i[n*NSN + r];
    Mbig_s[i] = v;
  }
  for (int i = tid; i < NPN*NPN*3; i += blockDim.x) {
    int n = i / 24, s = i % 24, r = s / 3, tau = s % 3;
    float v;
    if (tau == 0) v = (n == r) ? 1.f : 0.f;
    else if (tau == 1) v = Aop[n*NPN + r];
    else               v = Aip[n*NPN + r];
    Mbig_p[i] = v;
  }
}

// ---------------- weight prep (fp16) ----------------
__device__ __forceinline__ float wsrc(const float* W, int Kdim, int tau, int i, int jj) {
  if (tau == 0) return W[(size_t)(0*Kdim+0)*512*256 + (size_t)i*256 + jj]
                     + W[(size_t)(1*Kdim+0)*512*256 + (size_t)i*256 + jj];
  int dir = (tau - 1) & 1;
  int k = (tau + 1) >> 1;
  return W[(size_t)(dir*Kdim + k)*512*256 + (size_t)i*256 + jj];
}

__global__ void prep_w(const float* __restrict__ Wz_s, const float* __restrict__ Wr_s, const float* __restrict__ Wh_s,
                       const float* __restrict__ Wz_p, const float* __restrict__ Wr_p, const float* __restrict__ Wh_p,
                       half_t* __restrict__ WX_s, half_t* __restrict__ WX_p,
                       half_t* __restrict__ WHzr_s, half_t* __restrict__ WHh_s,
                       half_t* __restrict__ WHzr_p, half_t* __restrict__ WHh_p) {
  const long c0 = (long)768*KHS;
  const long c1 = c0 + (long)768*KHP;
  const long c2 = c1 + (long)2560*256;
  const long c3 = c2 + (long)1280*256;
  const long c4 = c3 + (long)1536*256;
  const long c5 = c4 + (long)768*256;
  for (long idx = (long)blockIdx.x*256 + threadIdx.x; idx < c5; idx += (long)gridDim.x*256) {
    if (idx < c0) {
      long x = idx; int j = (int)(x / KHS), c = (int)(x % KHS); int tau = c >> 8;
      const float* W = (j < 256) ? Wz_s : (j < 512) ? Wr_s : Wh_s;
      WX_s[x] = (half_t)wsrc(W, 3, tau, c & 255, j & 255);
    } else if (idx < c1) {
      long x = idx - c0; int j = (int)(x / KHP), c = (int)(x % KHP); int tau = c >> 8;
      const float* W = (j < 256) ? Wz_p : (j < 512) ? Wr_p : Wh_p;
      WX_p[x] = (half_t)wsrc(W, 2, tau, c & 255, j & 255);
    } else if (idx < c2) {
      long x = idx - c1; int cc = (int)(x >> 8), f = (int)(x & 255);
      int tau = cc / 512, j = cc % 512;
      const float* W = (j < 256) ? Wz_s : Wr_s;
      WHzr_s[(size_t)cc*256 + f] = (half_t)wsrc(W, 3, tau, 256 + f, j & 255);
    } else if (idx < c3) {
      long x = idx - c2; int cc = (int)(x >> 8), f = (int)(x & 255);
      int tau = cc >> 8, j = cc & 255;
      WHh_s[(size_t)cc*256 + f] = (half_t)wsrc(Wh_s, 3, tau, 256 + f, j);
    } else if (idx < c4) {
      long x = idx - c3; int cc = (int)(x >> 8), f = (int)(x & 255);
      int tau = cc / 512, j = cc % 512;
      const float* W = (j < 256) ? Wz_p : Wr_p;
      WHzr_p[(size_t)cc*256 + f] = (half_t)wsrc(W, 2, tau, 256 + f, j & 255);
    } else {
      long x = idx - c4; int cc = (int)(x >> 8), f = (int)(x & 255);
      int tau = cc >> 8, j = cc & 255;
      WHh_p[(size_t)cc*256 + f] = (half_t)wsrc(Wh_p, 2, tau, 256 + f, j);
    }
  }
}

__global__ void zero_f(float* p, long n) {
  long i = (long)blockIdx.x*256 + threadIdx.x;
  if (i < n) p[i] = 0.f;
}

// ---------------- cheb expansion of X (precompute A), fp16 ----------------
__global__ __launch_bounds__(256) void chebx(const float* __restrict__ xdis, const float* __restrict__ xpre,
                                             const float* __restrict__ Ms_s, const float* __restrict__ Ms_p,
                                             half_t* __restrict__ XTs, half_t* __restrict__ XTp, int t0) {
  __shared__ float Xc[NSN*256];
  __shared__ float Ml[4*NSN*NSN];
  int bb = blockIdx.x, tid = threadIdx.x;
  bool isP = bb >= NB*TCH;
  int q = isP ? bb - NB*TCH : bb;
  int b = q % NB, tp = q / NB;
  int N = isP ? NPN : NSN, nt = isP ? 3 : 5, KX = nt << 8;
  const float* X = isP ? (xpre + (size_t)(b*TT + t0 + tp)*NPN*256)
                       : (xdis + (size_t)(b*TT + t0 + tp)*NSN*256);
  for (int i = tid; i < N*64; i += 256) ((float4*)Xc)[i] = ((const float4*)X)[i];
  int nm = (nt-1)*N*N;
  const float* Msrc = isP ? Ms_p : Ms_s;
  for (int i = tid; i < nm; i += 256) Ml[i] = Msrc[i];
  __syncthreads();
  half_t* XT = isP ? XTp : XTs;
  size_t rowbase = (size_t)(tp*NB + b)*N;
  int kc8 = KX >> 3, nch = N * kc8;
  for (int i = tid; i < nch; i += 256) {
    int n = i / kc8, c8 = i - n*kc8;
    int tau = c8 >> 5, f0 = (c8 & 31) << 3;
    float v[8];
    if (tau == 0) {
      const float* xr0 = Xc + n*256 + f0;
#pragma unroll
      for (int j = 0; j < 8; ++j) v[j] = xr0[j];
    } else {
      const float* M = Ml + (tau-1)*N*N + n*N;
#pragma unroll
      for (int j = 0; j < 8; ++j) v[j] = 0.f;
      for (int r = 0; r < N; ++r) {
        float m = M[r];
        const float* xr = Xc + r*256 + f0;
#pragma unroll
        for (int j = 0; j < 8; ++j) v[j] += m*xr[j];
      }
    }
    union { uint4 q; half_t u[8]; } hv;
#pragma unroll
    for (int j = 0; j < 8; ++j) hv.u[j] = (half_t)v[j];
    *(uint4*)(XT + (rowbase + n)*(size_t)KX + ((size_t)c8 << 3)) = hv.q;
  }
}

// ---------------- precompute GEMM (R8, unchanged) ----------------
__global__ __launch_bounds__(512) void gemm_pre(
    const half_t* __restrict__ A0, const half_t* __restrict__ B0, int K0,
    int rbS, int cbTot,
    const half_t* __restrict__ A1, const half_t* __restrict__ B1, int K1,
    half_t* __restrict__ Px0, half_t* __restrict__ Px1,
    const float* __restrict__ bz0, const float* __restrict__ br0, const float* __restrict__ bh0,
    const float* __restrict__ bz1, const float* __restrict__ br1, const float* __restrict__ bh1) {
  __shared__ __align__(16) half_t sbuf[3][12288];
  int id = blockIdx.x;
  int xx = id & 7, kq = id >> 3;
  int rbTot8 = (gridDim.x / cbTot) >> 3;
  int rb = xx*rbTot8 + kq / cbTot;
  int cb = kq - (kq / cbTot)*cbTot;

  bool isP = rb >= rbS;
  const half_t* A = isP ? A1 : A0;
  const half_t* B = isP ? B1 : B0;
  int K = isP ? K1 : K0;
  int row0 = (isP ? rb - rbS : rb) * 64;
  int col0 = cb * 128;
  int tid = threadIdx.x, lane = tid & 63, w = tid >> 6;
  int l15 = lane & 15, l4 = lane >> 4;
  int wr = (w >> 2) * 32, wc = (w & 3) * 32;

  const half_t* srcb[3];
  int ldso[3];
#pragma unroll
  for (int j = 0; j < 3; ++j) {
    int c = ((j*8 + w) << 6) + lane;
    const half_t* base;
    if (c < 512) {
      int r = c >> 3, kb = c & 7;
      base = A + (size_t)(row0 + r)*K + ((kb ^ (r & 7)) << 3);
    } else {
      int d = c - 512, r = d >> 3, kb = d & 7;
      base = B + (size_t)(col0 + r)*K + ((kb ^ (r & 7)) << 3);
    }
    srcb[j] = base;
    ldso[j] = c << 3;
  }

  f32x4 acc[2][2];
#pragma unroll
  for (int i = 0; i < 2; ++i)
#pragma unroll
    for (int j = 0; j < 2; ++j) acc[i][j] = (f32x4){0.f,0.f,0.f,0.f};

  int nk = K >> 6;
#define STAGEP(K0E, BUFP)  { half_t* _b = (BUFP); _Pragma("unroll") \
    for (int j = 0; j < 3; ++j) gl16(srcb[j] + (K0E), _b + ldso[j]); }

  STAGEP(0,   &sbuf[0][0]);
  STAGEP(64,  &sbuf[1][0]);
  STAGEP(128, &sbuf[2][0]);

  for (int k = 0; k < nk; ++k) {
    int rem = nk - 1 - k;
    if (rem >= 2)      asm volatile("s_waitcnt vmcnt(6)" ::: "memory");
    else if (rem == 1) asm volatile("s_waitcnt vmcnt(3)" ::: "memory");
    else               asm volatile("s_waitcnt vmcnt(0)" ::: "memory");
    __builtin_amdgcn_s_barrier();
    const half_t* cur = &sbuf[k % 3][0];
    const half_t* cB = cur + 4096;
#pragma unroll
    for (int kk = 0; kk < 2; ++kk) {
      f16x8 af[2], bq[2];
#pragma unroll
      for (int mi = 0; mi < 2; ++mi) {
        int r = wr + mi*16 + l15;
        int sb = (kk*4 + l4) ^ (r & 7);
        af[mi] = *(const f16x8*)&cur[r*64 + sb*8];
      }
#pragma unroll
      for (int ni = 0; ni < 2; ++ni) {
        int r = wc + ni*16 + l15;
        int sb = (kk*4 + l4) ^ (r & 7);
        bq[ni] = *(const f16x8*)&cB[r*64 + sb*8];
      }
#pragma unroll
      for (int mi = 0; mi < 2; ++mi)
#pragma unroll
        for (int ni = 0; ni < 2; ++ni)
          acc[mi][ni] = __builtin_amdgcn_mfma_f32_16x16x32_f16(af[mi], bq[ni], acc[mi][ni], 0, 0, 0);
    }
    __builtin_amdgcn_s_barrier();
    if (k + 3 < nk) STAGEP((k + 3) << 6, &sbuf[k % 3][0]);
  }
#undef STAGEP

  half_t* PxO = isP ? Px1 : Px0;
#pragma unroll
  for (int mi = 0; mi < 2; ++mi)
#pragma unroll
    for (int ni = 0; ni < 2; ++ni) {
      int colg = col0 + wc + ni*16 + l15;
      const float* bias = (colg < 256) ? (isP ? bz1 : bz0)
                        : (colg < 512) ? (isP ? br1 : br0)
                                       : (isP ? bh1 : bh0);
#pragma unroll
      for (int rg = 0; rg < 4; ++rg) {
        int grow = row0 + wr + mi*16 + l4*4 + rg;
        PxO[(size_t)grow*NPRE + colg] = (half_t)(acc[mi][ni][rg] + bias[colg & 255]);
      }
    }
}

// ---------------- device job bodies (R8 gemm_y / contract_k verbatim) ----------------
__device__ __forceinline__ void gemm_y_job(int id, int tid,
    const half_t* __restrict__ A0, const half_t* __restrict__ B0, half_t* __restrict__ C0, int NC0, int cb0, int nb0,
    const half_t* __restrict__ A1, const half_t* __restrict__ B1, half_t* __restrict__ C1, int NC1, int cb1,
    half_t* sbuf) {
  int rb, cb; const half_t *A, *B; half_t* C; int NC;
  if (id < nb0) { rb = id / cb0; cb = id % cb0; A = A0; B = B0; C = C0; NC = NC0; }
  else { int q = id - nb0; rb = q / cb1; cb = q % cb1; A = A1; B = B1; C = C1; NC = NC1; }
  int row0 = rb*64, col0 = cb*128;
  int lane = tid & 63, w = tid >> 6;
  int l15 = lane & 15, l4 = lane >> 4;
  int wr = (w >> 2) * 32, wc = (w & 3) * 32;

  const half_t* srcb[3];
  int ldso[3];
#pragma unroll
  for (int j = 0; j < 3; ++j) {
    int c = ((j*8 + w) << 6) + lane;
    const half_t* base;
    if (c < 512) {
      int r = c >> 3, kb = c & 7;
      base = A + (size_t)(row0 + r)*256 + ((kb ^ (r & 7)) << 3);
    } else {
      int d = c - 512, r = d >> 3, kb = d & 7;
      base = B + (size_t)(col0 + r)*256 + ((kb ^ (r & 7)) << 3);
    }
    srcb[j] = base;
    ldso[j] = c << 3;
  }

  f32x4 acc[2][2];
#pragma unroll
  for (int i = 0; i < 2; ++i)
#pragma unroll
    for (int j = 0; j < 2; ++j) acc[i][j] = (f32x4){0.f,0.f,0.f,0.f};

#define STAGEY(K0E, BUFP)  { half_t* _b = (BUFP); _Pragma("unroll") \
    for (int j = 0; j < 3; ++j) gl16(srcb[j] + (K0E), _b + ldso[j]); }

  STAGEY(0,   sbuf);
  STAGEY(64,  sbuf + 12288);
  STAGEY(128, sbuf + 24576);

  for (int k = 0; k < 4; ++k) {
    int rem = 3 - k;
    if (rem >= 2)      asm volatile("s_waitcnt vmcnt(6)" ::: "memory");
    else if (rem == 1) asm volatile("s_waitcnt vmcnt(3)" ::: "memory");
    else               asm volatile("s_waitcnt vmcnt(0)" ::: "memory");
    __builtin_amdgcn_s_barrier();
    const half_t* cur = sbuf + (k % 3)*12288;
    const half_t* cB = cur + 4096;
#pragma unroll
    for (int kk = 0; kk < 2; ++kk) {
      f16x8 af[2], bq[2];
#pragma unroll
      for (int mi = 0; mi < 2; ++mi) {
        int r = wr + mi*16 + l15;
        int sb = (kk*4 + l4) ^ (r & 7);
        af[mi] = *(const f16x8*)&cur[r*64 + sb*8];
      }
#pragma unroll
      for (int ni = 0; ni < 2; ++ni) {
        int r = wc + ni*16 + l15;
        int sb = (kk*4 + l4) ^ (r & 7);
        bq[ni] = *(const f16x8*)&cB[r*64 + sb*8];
      }
#pragma unroll
      for (int mi = 0; mi < 2; ++mi)
#pragma unroll
        for (int ni = 0; ni < 2; ++ni)
          acc[mi][ni] = __builtin_amdgcn_mfma_f32_16x16x32_f16(af[mi], bq[ni], acc[mi][ni], 0, 0, 0);
    }
    __builtin_amdgcn_s_barrier();
    if (k + 3 < 4) STAGEY((k + 3) << 6, sbuf + (k % 3)*12288);
  }
#undef STAGEY

#pragma unroll
  for (int mi = 0; mi < 2; ++mi)
#pragma unroll
    for (int ni = 0; ni < 2; ++ni) {
      int colg = col0 + wc + ni*16 + l15;
#pragma unroll
      for (int rg = 0; rg < 4; ++rg) {
        int grow = row0 + wr + mi*16 + l4*4 + rg;
        C[(size_t)grow*NC + colg] = (half_t)acc[mi][ni][rg];
      }
    }
}

template<int GATE>
__device__ __forceinline__ void contract_job(int id, int tid,
    const half_t* __restrict__ Ys, const half_t* __restrict__ Yp,
    const half_t* __restrict__ Px_s, const half_t* __restrict__ Px_p,
    const float* __restrict__ Mb_s, const float* __restrict__ Mb_p,
    const float* __restrict__ Hin, float* __restrict__ Z,
    half_t* __restrict__ Out_s, half_t* __restrict__ Out_p,
    float* __restrict__ Hout, float* Yl, float* Mbl) {
  constexpr int JB = GATE ? 2 : 4;
  constexpr int JW = GATE ? 256 : 512;
  __syncthreads();   // previous Yl/sbuf users done
  bool isP = id >= NB*JB;
  int q = isP ? id - NB*JB : id;
  int b = q / JB, jb = q - b*JB;
  int N = isP ? NPN : NSN, ntau = isP ? 3 : 5;
  int nseg = N * ntau;
  int NC = ntau * JW;
  const half_t* Y = isP ? Yp : Ys;
  const float* Mbg = isP ? Mb_p : Mb_s;
  int tot8 = nseg << 4;
  for (int i = tid; i < tot8; i += 512) {
    int seg = i >> 4, q8 = i & 15;
    int r = seg / ntau, tau = seg - r*ntau;
    union { uint4 qq; half_t u[8]; } uu;
    uu.qq = *(const uint4*)&Y[(size_t)(b*N + r)*NC + tau*JW + jb*128 + (q8 << 3)];
    float* dst = Yl + (seg << 7) + (q8 << 3);
#pragma unroll
    for (int e = 0; e < 8; ++e) dst[e] = (float)uu.u[e];
  }
  for (int i = tid; i < N*nseg; i += 512) Mbl[i] = Mbg[i];
  __syncthreads();
  f32x4* Yl4 = (f32x4*)Yl;
  const half_t* Px = isP ? Px_p : Px_s;
  half_t* Out = isP ? Out_p : Out_s;
  int hoff = isP ? NSN : 0;
  int nout4 = N << 5;
  for (int o = tid; o < nout4; o += 512) {
    int n = o >> 5, j4 = o & 31;
    int j = jb*128 + (j4 << 2);
    f32x4 p = (f32x4){0.f,0.f,0.f,0.f};
    const float* mrow = Mbl + n*nseg;
    for (int s = 0; s < nseg; ++s) {
      float m = mrow[s];
      f32x4 y = Yl4[(s << 5) + j4];
      p += m*y;
    }
    union { uint2 qq; half_t u[4]; } pu;
    pu.qq = *(const uint2*)&Px[(size_t)(b*N + n)*NPRE + (GATE ? 512 : 0) + j];
#pragma unroll
    for (int e = 0; e < 4; ++e) p[e] += (float)pu.u[e];
    if constexpr (GATE == 0) {
      if (j < 256) {
        f32x4 sg;
#pragma unroll
        for (int e = 0; e < 4; ++e) sg[e] = 1.f/(1.f + expf(-p[e]));
        *(f32x4*)&Z[((size_t)b*NN + hoff + n)*256 + j] = sg;
      } else {
        int f = j - 256;
        f32x4 h = *(const f32x4*)&Hin[((size_t)b*NN + hoff + n)*256 + f];
        union { uint2 qq; half_t u[4]; } ho;
#pragma unroll
        for (int e = 0; e < 4; ++e) ho.u[e] = (half_t)(h[e]/(1.f + expf(-p[e])));
        *(uint2*)(Out + (size_t)(b*N + n)*256 + f) = ho.qq;
      }
    } else {
      size_t hidx = ((size_t)b*NN + hoff + n)*256 + j;
      f32x4 zv = *(const f32x4*)&Z[hidx];
      f32x4 hv = *(const f32x4*)&Hin[hidx];
      f32x4 hn;
      union { uint2 qq; half_t u[4]; } ho;
#pragma unroll
      for (int e = 0; e < 4; ++e) {
        float ht = tanhf(p[e]);
        hn[e] = zv[e]*hv[e] + (1.f - zv[e])*ht;
        ho.u[e] = (half_t)hn[e];
      }
      *(f32x4*)&Hout[hidx] = hn;
      *(uint2*)(Out + (size_t)(b*N + n)*256 + j) = ho.qq;
    }
  }
}

// ---------------- persistent recurrence: tree-arrival + read-only-spin barrier ----------------
__global__ __launch_bounds__(512, 4) void rec_all(
    half_t* Hf_s, half_t* Hf_p, half_t* gHf_s, half_t* gHf_p,
    const half_t* WHzr_s, const half_t* WHzr_p, const half_t* WHh_s, const half_t* WHh_p,
    const half_t* Px_s, const half_t* Px_p,
    const float* Mb_s, const float* Mb_p,
    float* H, float* Z, half_t* Y_s, half_t* Y_p,
    unsigned* cnt) {
  __shared__ __align__(16) half_t sbuf[3*12288];   // 72KB; overlaid as Yl/Mbl in contract phases
  float* Yl = (float*)sbuf;
  float* Mbl = Yl + 12800;
  int bid = blockIdx.x, tid = threadIdx.x;
  unsigned G = gridDim.x;
  unsigned bidx = 0;

  // cnt layout: arrival sub-counters at cnt[i*32], i=0..7 (128B apart); release at cnt[256].
#define GBAR() do {                                                            \
    __threadfence(); __syncthreads(); ++bidx;                                  \
    if (tid == 0) {                                                            \
      __hip_atomic_fetch_add(&cnt[(bid & 7) << 5], 1u, __ATOMIC_RELEASE,       \
                             __HIP_MEMORY_SCOPE_AGENT);                        \
      if (bid == 0) {                                                          \
        for (;;) {                                                             \
          unsigned s = 0;                                                      \
          for (int i = 0; i < 8; ++i)                                          \
            s += __hip_atomic_load(&cnt[i << 5], __ATOMIC_ACQUIRE,             \
                                   __HIP_MEMORY_SCOPE_AGENT);                  \
          if (s >= G * bidx) break;                                            \
          __builtin_amdgcn_s_sleep(2);                                         \
        }                                                                      \
        __hip_atomic_store(&cnt[256], bidx, __ATOMIC_RELEASE,                  \
                           __HIP_MEMORY_SCOPE_AGENT);                          \
      } else {                                                                 \
        while (__hip_atomic_load(&cnt[256], __ATOMIC_ACQUIRE,                  \
                                 __HIP_MEMORY_SCOPE_AGENT) < bidx)             \
          __builtin_amdgcn_s_sleep(8);                                         \
      }                                                                        \
    }                                                                          \
    __syncthreads(); __threadfence();                                          \
  } while (0)

  for (int t = 0; t < TT; ++t) {
    const half_t* PxS = Px_s + (size_t)t*NB*NSN*NPRE;
    const half_t* PxP = Px_p + (size_t)t*NB*NPN*NPRE;
    for (int j = bid; j < 992; j += (int)G)
      gemm_y_job(j, tid, Hf_s, WHzr_s, Y_s, 2560, 20, 800,
                 Hf_p, WHzr_p, Y_p, 1536, 12, sbuf);
    GBAR();
    for (int j = bid; j < 1024; j += (int)G)
      contract_job<0>(j, tid, Y_s, Y_p, PxS, PxP, Mb_s, Mb_p,
                      H, Z, gHf_s, gHf_p, nullptr, Yl, Mbl);
    GBAR();
    for (int j = bid; j < 496; j += (int)G)
      gemm_y_job(j, tid, gHf_s, WHh_s, Y_s, 1280, 10, 400,
                 gHf_p, WHh_p, Y_p, 768, 6, sbuf);
    GBAR();
    for (int j = bid; j < 512; j += (int)G)
      contract_job<1>(j, tid, Y_s, Y_p, PxS, PxP, Mb_s, Mb_p,
                      H, Z, Hf_s, Hf_p, H, Yl, Mbl);
    GBAR();
  }
#undef GBAR
}

// ---------------- readout ----------------
__global__ __launch_bounds__(256) void readout_k(const float* __restrict__ H, const float* __restrict__ W_ro,
                                                 const float* __restrict__ b_ro, const float* __restrict__ W_ag,
                                                 const float* __restrict__ b_ag, float* __restrict__ out) {
  __shared__ float red[256];
  __shared__ float o1[NN];
  int b = blockIdx.x, tid = threadIdx.x;
  float wro = W_ro[tid];
  for (int n = 0; n < NN; ++n) {
    red[tid] = H[((size_t)b*NN + n)*256 + tid] * wro;
    __syncthreads();
    for (int s = 128; s > 0; s >>= 1) { if (tid < s) red[tid] += red[tid+s]; __syncthreads(); }
    if (tid == 0) o1[n] = red[0] + b_ro[0];
    __syncthreads();
  }
  if (tid < 5) {
    float s = b_ag[tid];
    for (int n = 0; n < NN; ++n) s += o1[n] * W_ag[n*5 + tid];
    out[b*5 + tid] = s;
  }
}

// ---------------- host ----------------
extern "C" void kernel_launch(void* const* d_in, const int* in_sizes, int n_in,
                              void* d_out, int out_size, void* d_ws, size_t ws_size,
                              hipStream_t stream) {
  const float* xdis = (const float*)d_in[0];
  const float* xpre = (const float*)d_in[1];
  const int*   ei_s = (const int*)d_in[2];
  const int*   ei_p = (const int*)d_in[3];
  const float* ew_s = (const float*)d_in[4];
  const float* ew_p = (const float*)d_in[5];
  const float* Wz_s = (const float*)d_in[6];
  const float* bz_s = (const float*)d_in[7];
  const float* Wr_s = (const float*)d_in[8];
  const float* br_s = (const float*)d_in[9];
  const float* Wh_s = (const float*)d_in[10];
  const float* bh_s = (const float*)d_in[11];
  const float* Wz_p = (const float*)d_in[12];
  const float* bz_p = (const float*)d_in[13];
  const float* Wr_p = (const float*)d_in[14];
  const float* br_p = (const float*)d_in[15];
  const float* Wh_p = (const float*)d_in[16];
  const float* bh_p = (const float*)d_in[17];
  const float* W_ro = (const float*)d_in[18];
  const float* b_ro = (const float*)d_in[19];
  const float* W_ag = (const float*)d_in[20];
  const float* b_ag = (const float*)d_in[21];
  float* out = (float*)d_out;
  (void)in_sizes; (void)n_in; (void)out_size; (void)ws_size;

  char* w = (char*)d_ws;
  size_t off = 0;
  auto alloc = [&](size_t bytes) { void* p = w + off; off = (off + bytes + 255) & ~(size_t)255; return p; };

  const size_t rowsXs = (size_t)TCH*NB*NSN, rowsXp = (size_t)TCH*NB*NPN;

  float* Ms_s = (float*)alloc(4*NSN*NSN*sizeof(float));
  float* Ms_p = (float*)alloc(2*NPN*NPN*sizeof(float));
  float* Mbig_s = (float*)alloc(NSN*100*sizeof(float));
  float* Mbig_p = (float*)alloc(NPN*24*sizeof(float));
  half_t* WX_s = (half_t*)alloc((size_t)768*KHS*2);
  half_t* WX_p = (half_t*)alloc((size_t)768*KHP*2);
  half_t* WHzr_s = (half_t*)alloc((size_t)2560*256*2);
  half_t* WHh_s  = (half_t*)alloc((size_t)1280*256*2);
  half_t* WHzr_p = (half_t*)alloc((size_t)1536*256*2);
  half_t* WHh_p  = (half_t*)alloc((size_t)768*256*2);
  half_t* XT_s = (half_t*)alloc(rowsXs*KHS*2);
  half_t* XT_p = (half_t*)alloc(rowsXp*KHP*2);
  half_t* Px_s = (half_t*)alloc((size_t)TT*NB*NSN*NPRE*2);
  half_t* Px_p = (half_t*)alloc((size_t)TT*NB*NPN*NPRE*2);
  half_t* Y_s = (half_t*)alloc((size_t)NB*NSN*2560*2);
  half_t* Y_p = (half_t*)alloc((size_t)NB*NPN*1536*2);
  float* H  = (float*)alloc((size_t)NB*NN*256*4);
  float* Z  = (float*)alloc((size_t)NB*NN*256*4);
  half_t* Hf  = (half_t*)alloc((size_t)NB*NN*256*2);
  half_t* gHf = (half_t*)alloc((size_t)NB*NN*256*2);
  unsigned* cnt = (unsigned*)alloc(2048);
  half_t* Hf_s = Hf,  * Hf_p = Hf + (size_t)NB*NSN*256;
  half_t* gHf_s = gHf, * gHf_p = gHf + (size_t)NB*NSN*256;

  graph_build<<<1, 64, 0, stream>>>(ei_s, ew_s, ei_p, ew_p, Ms_s, Ms_p, Mbig_s, Mbig_p);
  prep_w<<<1024, 256, 0, stream>>>(Wz_s, Wr_s, Wh_s, Wz_p, Wr_p, Wh_p,
                                   WX_s, WX_p, WHzr_s, WHh_s, WHzr_p, WHh_p);
  const long nH = (long)NB*NN*256;
  zero_f<<<(nH + 255)/256, 256, 0, stream>>>(H, nH);
  zero_f<<<(nH/2 + 255)/256, 256, 0, stream>>>((float*)Hf, nH/2);
  zero_f<<<2, 256, 0, stream>>>((float*)cnt, 512);

  // ---- precompute Px ----
  for (int t0 = 0; t0 < TT; t0 += TCH) {
    chebx<<<2*NB*TCH, 256, 0, stream>>>(xdis, xpre, Ms_s, Ms_p, XT_s, XT_p, t0);
    gemm_pre<<<224*6, 512, 0, stream>>>(
        XT_s, WX_s, KHS, 160, 6,
        XT_p, WX_p, KHP,
        Px_s + (size_t)t0*NB*NSN*NPRE, Px_p + (size_t)t0*NB*NPN*NPRE,
        bz_s, br_s, bh_s, bz_p, br_p, bh_p);
  }

  // ---- recurrence: single persistent kernel, 512 blocks (2/CU guaranteed: 72KB LDS, <=128 VGPR) ----
  rec_all<<<512, 512, 0, stream>>>(
      Hf_s, Hf_p, gHf_s, gHf_p,
      WHzr_s, WHzr_p, WHh_s, WHh_p,
      Px_s, Px_p, Mbig_s, Mbig_p,
      H, Z, Y_s, Y_p, cnt);

  readout_k<<<NB, 256, 0, stream>>>(H, W_ro, b_ro, W_ag, b_ag, out);
}

// Round 16
// 1656.958 us; speedup vs baseline: 14.5141x; 14.5141x over previous
//
#include <hip/hip_runtime.h>
#include <stdint.h>

#define NSN 20
#define NPN 8
#define NB 128
#define TT 24
#define NN 28
#define ES 100
#define EP 32
#define KHS 1280
#define KHP 768
#define NPRE 768
#define TCH 8

typedef _Float16 half_t;
typedef __attribute__((ext_vector_type(8))) _Float16 f16x8;
typedef __attribute__((ext_vector_type(4))) float f32x4;

__device__ __forceinline__ void gl16(const half_t* g, half_t* l) {
  __builtin_amdgcn_global_load_lds((const __attribute__((address_space(1))) void*)g,
                                   (__attribute__((address_space(3))) void*)l, 16, 0, 0);
}

// ---------------- graph build (edges staged in LDS) ----------------
__global__ void graph_build(const int* __restrict__ ei_s, const float* __restrict__ ew_s,
                            const int* __restrict__ ei_p, const float* __restrict__ ew_p,
                            float* __restrict__ Ms_s, float* __restrict__ Ms_p) {
  __shared__ float Ao[NSN*NSN], Aiw[NSN*NSN], dgo[NSN], dgi[NSN];
  __shared__ float Aop[NPN*NPN], Aip[NPN*NPN], dgop[NPN], dgip[NPN];
  __shared__ int eis[2*ES]; __shared__ float ews[ES];
  __shared__ int eip[2*EP]; __shared__ float ewp[EP];
  int tid = threadIdx.x;
  for (int i = tid; i < 2*ES; i += blockDim.x) eis[i] = ei_s[i];
  for (int i = tid; i < ES; i += blockDim.x) ews[i] = ew_s[i];
  for (int i = tid; i < 2*EP; i += blockDim.x) eip[i] = ei_p[i];
  for (int i = tid; i < EP; i += blockDim.x) ewp[i] = ew_p[i];
  for (int i = tid; i < NSN*NSN; i += blockDim.x) { Ao[i] = 0.f; Aiw[i] = 0.f; }
  for (int i = tid; i < NPN*NPN; i += blockDim.x) { Aop[i] = 0.f; Aip[i] = 0.f; }
  if (tid < NSN) { dgo[tid] = 0.f; dgi[tid] = 0.f; }
  if (tid < NPN) { dgop[tid] = 0.f; dgip[tid] = 0.f; }
  __syncthreads();
  if (tid == 0) {
    for (int e = 0; e < ES; ++e) { int r = eis[e], c = eis[ES+e]; float w = ews[e]; dgo[r] += w; dgi[c] += w; }
    for (int e = 0; e < ES; ++e) { int r = eis[e], c = eis[ES+e]; Ao[c*NSN+r] += 1.f/dgo[r]; Aiw[c*NSN+r] += 1.f/dgi[r]; }
  }
  if (tid == 1) {
    for (int e = 0; e < EP; ++e) { int r = eip[e], c = eip[EP+e]; float w = ewp[e]; dgop[r] += w; dgip[c] += w; }
    for (int e = 0; e < EP; ++e) { int r = eip[e], c = eip[EP+e]; Aop[c*NPN+r] += 1.f/dgop[r]; Aip[c*NPN+r] += 1.f/dgip[r]; }
  }
  __syncthreads();
  for (int i = tid; i < NSN*NSN; i += blockDim.x) {
    int r = i / NSN, c = i % NSN;
    float so = 0.f, si = 0.f;
    for (int k = 0; k < NSN; ++k) { so += Ao[r*NSN+k]*Ao[k*NSN+c]; si += Aiw[r*NSN+k]*Aiw[k*NSN+c]; }
    Ms_s[0*NSN*NSN + i] = Ao[i];
    Ms_s[1*NSN*NSN + i] = Aiw[i];
    Ms_s[2*NSN*NSN + i] = 2.f*so - (r==c ? 1.f : 0.f);
    Ms_s[3*NSN*NSN + i] = 2.f*si - (r==c ? 1.f : 0.f);
  }
  for (int i = tid; i < NPN*NPN; i += blockDim.x) {
    Ms_p[0*NPN*NPN + i] = Aop[i];
    Ms_p[1*NPN*NPN + i] = Aip[i];
  }
}

// ---------------- weight prep (all single-plane fp16) ----------------
__device__ __forceinline__ float wsrc(const float* W, int Kdim, int tau, int i, int jj) {
  if (tau == 0) return W[(size_t)(0*Kdim+0)*512*256 + (size_t)i*256 + jj]
                     + W[(size_t)(1*Kdim+0)*512*256 + (size_t)i*256 + jj];
  int dir = (tau - 1) & 1;
  int k = (tau + 1) >> 1;
  return W[(size_t)(dir*Kdim + k)*512*256 + (size_t)i*256 + jj];
}

__global__ void prep_w(const float* __restrict__ Wz_s, const float* __restrict__ Wr_s, const float* __restrict__ Wh_s,
                       const float* __restrict__ Wz_p, const float* __restrict__ Wr_p, const float* __restrict__ Wh_p,
                       half_t* __restrict__ WX_s, half_t* __restrict__ WX_p,
                       half_t* __restrict__ WHzr_s, half_t* __restrict__ WHh_s,
                       half_t* __restrict__ WHzr_p, half_t* __restrict__ WHh_p) {
  const long c0 = (long)768*KHS;
  const long c1 = c0 + (long)768*KHP;
  const long c2 = c1 + (long)2560*256;
  const long c3 = c2 + (long)1280*256;
  const long c4 = c3 + (long)1536*256;
  const long c5 = c4 + (long)768*256;
  for (long idx = (long)blockIdx.x*256 + threadIdx.x; idx < c5; idx += (long)gridDim.x*256) {
    if (idx < c0) {
      long x = idx; int j = (int)(x / KHS), c = (int)(x % KHS); int tau = c >> 8;
      const float* W = (j < 256) ? Wz_s : (j < 512) ? Wr_s : Wh_s;
      WX_s[x] = (half_t)wsrc(W, 3, tau, c & 255, j & 255);
    } else if (idx < c1) {
      long x = idx - c0; int j = (int)(x / KHP), c = (int)(x % KHP); int tau = c >> 8;
      const float* W = (j < 256) ? Wz_p : (j < 512) ? Wr_p : Wh_p;
      WX_p[x] = (half_t)wsrc(W, 2, tau, c & 255, j & 255);
    } else if (idx < c2) {
      long x = idx - c1; int cc = (int)(x >> 8), f = (int)(x & 255);
      int tau = cc / 512, j = cc % 512;
      const float* W = (j < 256) ? Wz_s : Wr_s;
      WHzr_s[(size_t)cc*256 + f] = (half_t)wsrc(W, 3, tau, 256 + f, j & 255);
    } else if (idx < c3) {
      long x = idx - c2; int cc = (int)(x >> 8), f = (int)(x & 255);
      int tau = cc >> 8, j = cc & 255;
      WHh_s[(size_t)cc*256 + f] = (half_t)wsrc(Wh_s, 3, tau, 256 + f, j);
    } else if (idx < c4) {
      long x = idx - c3; int cc = (int)(x >> 8), f = (int)(x & 255);
      int tau = cc / 512, j = cc % 512;
      const float* W = (j < 256) ? Wz_p : Wr_p;
      WHzr_p[(size_t)cc*256 + f] = (half_t)wsrc(W, 2, tau, 256 + f, j & 255);
    } else {
      long x = idx - c4; int cc = (int)(x >> 8), f = (int)(x & 255);
      int tau = cc >> 8, j = cc & 255;
      WHh_p[(size_t)cc*256 + f] = (half_t)wsrc(Wh_p, 2, tau, 256 + f, j);
    }
  }
}

__global__ void zero_f(float* p, long n) {
  long i = (long)blockIdx.x*256 + threadIdx.x;
  if (i < n) p[i] = 0.f;
}

// ---------------- cheb expansion of X (precompute A), fp16 ----------------
__global__ __launch_bounds__(256) void chebx(const float* __restrict__ xdis, const float* __restrict__ xpre,
                                             const float* __restrict__ Ms_s, const float* __restrict__ Ms_p,
                                             half_t* __restrict__ XTs, half_t* __restrict__ XTp, int t0) {
  __shared__ float Xc[NSN*256];
  __shared__ float Ml[4*NSN*NSN];
  int bb = blockIdx.x, tid = threadIdx.x;
  bool isP = bb >= NB*TCH;
  int q = isP ? bb - NB*TCH : bb;
  int b = q % NB, tp = q / NB;
  int N = isP ? NPN : NSN, nt = isP ? 3 : 5, KX = nt << 8;
  const float* X = isP ? (xpre + (size_t)(b*TT + t0 + tp)*NPN*256)
                       : (xdis + (size_t)(b*TT + t0 + tp)*NSN*256);
  for (int i = tid; i < N*64; i += 256) ((float4*)Xc)[i] = ((const float4*)X)[i];
  int nm = (nt-1)*N*N;
  const float* Msrc = isP ? Ms_p : Ms_s;
  for (int i = tid; i < nm; i += 256) Ml[i] = Msrc[i];
  __syncthreads();
  half_t* XT = isP ? XTp : XTs;
  size_t rowbase = (size_t)(tp*NB + b)*N;
  int kc8 = KX >> 3, nch = N * kc8;
  for (int i = tid; i < nch; i += 256) {
    int n = i / kc8, c8 = i - n*kc8;
    int tau = c8 >> 5, f0 = (c8 & 31) << 3;
    float v[8];
    if (tau == 0) {
      const float* xr0 = Xc + n*256 + f0;
#pragma unroll
      for (int j = 0; j < 8; ++j) v[j] = xr0[j];
    } else {
      const float* M = Ml + (tau-1)*N*N + n*N;
#pragma unroll
      for (int j = 0; j < 8; ++j) v[j] = 0.f;
      for (int r = 0; r < N; ++r) {
        float m = M[r];
        const float* xr = Xc + r*256 + f0;
#pragma unroll
        for (int j = 0; j < 8; ++j) v[j] += m*xr[j];
      }
    }
    union { uint4 q; half_t u[8]; } hv;
#pragma unroll
    for (int j = 0; j < 8; ++j) hv.u[j] = (half_t)v[j];
    *(uint4*)(XT + (rowbase + n)*(size_t)KX + ((size_t)c8 << 3)) = hv.q;
  }
}

// ---------------- precompute GEMM: fp16 1-term, 64x128 tile, BK=64, ring-3 72KB ----------------
__global__ __launch_bounds__(512) void gemm_pre(
    const half_t* __restrict__ A0, const half_t* __restrict__ B0, int K0,
    int rbS, int cbTot,
    const half_t* __restrict__ A1, const half_t* __restrict__ B1, int K1,
    half_t* __restrict__ Px0, half_t* __restrict__ Px1,
    const float* __restrict__ bz0, const float* __restrict__ br0, const float* __restrict__ bh0,
    const float* __restrict__ bz1, const float* __restrict__ br1, const float* __restrict__ bh1) {
  __shared__ __align__(16) half_t sbuf[3][12288];
  int id = blockIdx.x;
  int xx = id & 7, kq = id >> 3;
  int rbTot8 = (gridDim.x / cbTot) >> 3;
  int rb = xx*rbTot8 + kq / cbTot;
  int cb = kq - (kq / cbTot)*cbTot;

  bool isP = rb >= rbS;
  const half_t* A = isP ? A1 : A0;
  const half_t* B = isP ? B1 : B0;
  int K = isP ? K1 : K0;
  int row0 = (isP ? rb - rbS : rb) * 64;
  int col0 = cb * 128;
  int tid = threadIdx.x, lane = tid & 63, w = tid >> 6;
  int l15 = lane & 15, l4 = lane >> 4;
  int wr = (w >> 2) * 32, wc = (w & 3) * 32;

  const half_t* srcb[3];
  int ldso[3];
#pragma unroll
  for (int j = 0; j < 3; ++j) {
    int c = ((j*8 + w) << 6) + lane;
    const half_t* base;
    if (c < 512) {
      int r = c >> 3, kb = c & 7;
      base = A + (size_t)(row0 + r)*K + ((kb ^ (r & 7)) << 3);
    } else {
      int d = c - 512, r = d >> 3, kb = d & 7;
      base = B + (size_t)(col0 + r)*K + ((kb ^ (r & 7)) << 3);
    }
    srcb[j] = base;
    ldso[j] = c << 3;
  }

  f32x4 acc[2][2];
#pragma unroll
  for (int i = 0; i < 2; ++i)
#pragma unroll
    for (int j = 0; j < 2; ++j) acc[i][j] = (f32x4){0.f,0.f,0.f,0.f};

  int nk = K >> 6;
#define STAGEP(K0E, BUFP)  { half_t* _b = (BUFP); _Pragma("unroll") \
    for (int j = 0; j < 3; ++j) gl16(srcb[j] + (K0E), _b + ldso[j]); }

  STAGEP(0,   &sbuf[0][0]);
  STAGEP(64,  &sbuf[1][0]);
  STAGEP(128, &sbuf[2][0]);

  for (int k = 0; k < nk; ++k) {
    int rem = nk - 1 - k;
    if (rem >= 2)      asm volatile("s_waitcnt vmcnt(6)" ::: "memory");
    else if (rem == 1) asm volatile("s_waitcnt vmcnt(3)" ::: "memory");
    else               asm volatile("s_waitcnt vmcnt(0)" ::: "memory");
    __builtin_amdgcn_s_barrier();
    const half_t* cur = &sbuf[k % 3][0];
    const half_t* cB = cur + 4096;
#pragma unroll
    for (int kk = 0; kk < 2; ++kk) {
      f16x8 af[2], bq[2];
#pragma unroll
      for (int mi = 0; mi < 2; ++mi) {
        int r = wr + mi*16 + l15;
        int sb = (kk*4 + l4) ^ (r & 7);
        af[mi] = *(const f16x8*)&cur[r*64 + sb*8];
      }
#pragma unroll
      for (int ni = 0; ni < 2; ++ni) {
        int r = wc + ni*16 + l15;
        int sb = (kk*4 + l4) ^ (r & 7);
        bq[ni] = *(const f16x8*)&cB[r*64 + sb*8];
      }
#pragma unroll
      for (int mi = 0; mi < 2; ++mi)
#pragma unroll
        for (int ni = 0; ni < 2; ++ni)
          acc[mi][ni] = __builtin_amdgcn_mfma_f32_16x16x32_f16(af[mi], bq[ni], acc[mi][ni], 0, 0, 0);
    }
    __builtin_amdgcn_s_barrier();
    if (k + 3 < nk) STAGEP((k + 3) << 6, &sbuf[k % 3][0]);
  }
#undef STAGEP

  half_t* PxO = isP ? Px1 : Px0;
#pragma unroll
  for (int mi = 0; mi < 2; ++mi)
#pragma unroll
    for (int ni = 0; ni < 2; ++ni) {
      int colg = col0 + wc + ni*16 + l15;
      const float* bias = (colg < 256) ? (isP ? bz1 : bz0)
                        : (colg < 512) ? (isP ? br1 : br0)
                                       : (isP ? bh1 : bh0);
#pragma unroll
      for (int rg = 0; rg < 4; ++rg) {
        int grow = row0 + wr + mi*16 + l4*4 + rg;
        PxO[(size_t)grow*NPRE + colg] = (half_t)(acc[mi][ni][rg] + bias[colg & 255]);
      }
    }
}

// ---------------- recurrence GEMM: Y(f16) = Hf @ WH^T, K=256, BK=64, ring-3 ----------------
__global__ __launch_bounds__(512) void gemm_y(
    const half_t* __restrict__ A0, const half_t* __restrict__ B0, half_t* __restrict__ C0, int NC0, int cb0, int nb0,
    const half_t* __restrict__ A1, const half_t* __restrict__ B1, half_t* __restrict__ C1, int NC1, int cb1) {
  __shared__ __align__(16) half_t sbuf[3][12288];
  int id = blockIdx.x;
  int rb, cb; const half_t *A, *B; half_t* C; int NC;
  if (id < nb0) { rb = id / cb0; cb = id % cb0; A = A0; B = B0; C = C0; NC = NC0; }
  else { int q = id - nb0; rb = q / cb1; cb = q % cb1; A = A1; B = B1; C = C1; NC = NC1; }
  int row0 = rb*64, col0 = cb*128;
  int tid = threadIdx.x, lane = tid & 63, w = tid >> 6;
  int l15 = lane & 15, l4 = lane >> 4;
  int wr = (w >> 2) * 32, wc = (w & 3) * 32;

  const half_t* srcb[3];
  int ldso[3];
#pragma unroll
  for (int j = 0; j < 3; ++j) {
    int c = ((j*8 + w) << 6) + lane;
    const half_t* base;
    if (c < 512) {
      int r = c >> 3, kb = c & 7;
      base = A + (size_t)(row0 + r)*256 + ((kb ^ (r & 7)) << 3);
    } else {
      int d = c - 512, r = d >> 3, kb = d & 7;
      base = B + (size_t)(col0 + r)*256 + ((kb ^ (r & 7)) << 3);
    }
    srcb[j] = base;
    ldso[j] = c << 3;
  }

  f32x4 acc[2][2];
#pragma unroll
  for (int i = 0; i < 2; ++i)
#pragma unroll
    for (int j = 0; j < 2; ++j) acc[i][j] = (f32x4){0.f,0.f,0.f,0.f};

#define STAGEY(K0E, BUFP)  { half_t* _b = (BUFP); _Pragma("unroll") \
    for (int j = 0; j < 3; ++j) gl16(srcb[j] + (K0E), _b + ldso[j]); }

  STAGEY(0,   &sbuf[0][0]);
  STAGEY(64,  &sbuf[1][0]);
  STAGEY(128, &sbuf[2][0]);

  for (int k = 0; k < 4; ++k) {
    int rem = 3 - k;
    if (rem >= 2)      asm volatile("s_waitcnt vmcnt(6)" ::: "memory");
    else if (rem == 1) asm volatile("s_waitcnt vmcnt(3)" ::: "memory");
    else               asm volatile("s_waitcnt vmcnt(0)" ::: "memory");
    __builtin_amdgcn_s_barrier();
    const half_t* cur = &sbuf[k % 3][0];
    const half_t* cB = cur + 4096;
#pragma unroll
    for (int kk = 0; kk < 2; ++kk) {
      f16x8 af[2], bq[2];
#pragma unroll
      for (int mi = 0; mi < 2; ++mi) {
        int r = wr + mi*16 + l15;
        int sb = (kk*4 + l4) ^ (r & 7);
        af[mi] = *(const f16x8*)&cur[r*64 + sb*8];
      }
#pragma unroll
      for (int ni = 0; ni < 2; ++ni) {
        int r = wc + ni*16 + l15;
        int sb = (kk*4 + l4) ^ (r & 7);
        bq[ni] = *(const f16x8*)&cB[r*64 + sb*8];
      }
#pragma unroll
      for (int mi = 0; mi < 2; ++mi)
#pragma unroll
        for (int ni = 0; ni < 2; ++ni)
          acc[mi][ni] = __builtin_amdgcn_mfma_f32_16x16x32_f16(af[mi], bq[ni], acc[mi][ni], 0, 0, 0);
    }
    __builtin_amdgcn_s_barrier();
    if (k + 3 < 4) STAGEY((k + 3) << 6, &sbuf[k % 3][0]);
  }
#undef STAGEY

#pragma unroll
  for (int mi = 0; mi < 2; ++mi)
#pragma unroll
    for (int ni = 0; ni < 2; ++ni) {
      int colg = col0 + wc + ni*16 + l15;
#pragma unroll
      for (int rg = 0; rg < 4; ++rg) {
        int grow = row0 + wr + mi*16 + l4*4 + rg;
        C[(size_t)grow*NC + colg] = (half_t)acc[mi][ni][rg];
      }
    }
}

// ---------------- node contraction + GRU epilogues ----------------
template<int GATE>
__global__ __launch_bounds__(256) void contract_k(
    const half_t* __restrict__ Ys, const half_t* __restrict__ Yp,
    const half_t* __restrict__ Px_s, const half_t* __restrict__ Px_p,
    const float* __restrict__ Mb_s, const float* __restrict__ Mb_p,
    const float* __restrict__ Hin, float* __restrict__ Z,
    half_t* __restrict__ Out_s, half_t* __restrict__ Out_p,
    float* __restrict__ Hout) {
  constexpr int JB = GATE ? 2 : 4;
  constexpr int JW = GATE ? 256 : 512;
  __shared__ float Yl[100*128];
  __shared__ float Mb[NSN*100];
  int id = blockIdx.x, tid = threadIdx.x;
  bool isP = id >= NB*JB;
  int q = isP ? id - NB*JB : id;
  int b = q / JB, jb = q % JB;
  int N = isP ? NPN : NSN, ntau = isP ? 3 : 5;
  int nseg = N * ntau;
  int NC = ntau * JW;
  const half_t* Y = isP ? Yp : Ys;
  const float* Mbg = isP ? Mb_p : Mb_s;
  int tot8 = nseg << 4;
  for (int i = tid; i < tot8; i += 256) {
    int seg = i >> 4, q8 = i & 15;
    int r = seg / ntau, tau = seg - r*ntau;
    union { uint4 qq; half_t u[8]; } uu;
    uu.qq = *(const uint4*)&Y[(size_t)(b*N + r)*NC + tau*JW + jb*128 + (q8 << 3)];
    float* dst = Yl + (seg << 7) + (q8 << 3);
#pragma unroll
    for (int e = 0; e < 8; ++e) dst[e] = (float)uu.u[e];
  }
  for (int i = tid; i < N*nseg; i += 256) Mb[i] = Mbg[i];
  __syncthreads();
  f32x4* Yl4 = (f32x4*)Yl;
  const half_t* Px = isP ? Px_p : Px_s;
  half_t* Out = isP ? Out_p : Out_s;
  int hoff = isP ? NSN : 0;
  int nout4 = N << 5;
  for (int o = tid; o < nout4; o += 256) {
    int n = o >> 5, j4 = o & 31;
    int j = jb*128 + (j4 << 2);
    f32x4 p = (f32x4){0.f,0.f,0.f,0.f};
    const float* mrow = Mb + n*nseg;
    for (int s = 0; s < nseg; ++s) {
      float m = mrow[s];
      f32x4 y = Yl4[(s << 5) + j4];
      p += m*y;
    }
    union { uint2 qq; half_t u[4]; } pu;
    pu.qq = *(const uint2*)&Px[(size_t)(b*N + n)*NPRE + (GATE ? 512 : 0) + j];
#pragma unroll
    for (int e = 0; e < 4; ++e) p[e] += (float)pu.u[e];
    if constexpr (GATE == 0) {
      if (j < 256) {
        f32x4 sg;
#pragma unroll
        for (int e = 0; e < 4; ++e) sg[e] = 1.f/(1.f + expf(-p[e]));
        *(f32x4*)&Z[((size_t)b*NN + hoff + n)*256 + j] = sg;
      } else {
        int f = j - 256;
        f32x4 h = *(const f32x4*)&Hin[((size_t)b*NN + hoff + n)*256 + f];
        union { uint2 qq; half_t u[4]; } ho;
#pragma unroll
        for (int e = 0; e < 4; ++e) ho.u[e] = (half_t)(h[e]/(1.f + expf(-p[e])));
        *(uint2*)(Out + (size_t)(b*N + n)*256 + f) = ho.qq;
      }
    } else {
      size_t hidx = ((size_t)b*NN + hoff + n)*256 + j;
      f32x4 zv = *(const f32x4*)&Z[hidx];
      f32x4 hv = *(const f32x4*)&Hin[hidx];
      f32x4 hn;
      union { uint2 qq; half_t u[4]; } ho;
#pragma unroll
      for (int e = 0; e < 4; ++e) {
        float ht = tanhf(p[e]);
        hn[e] = zv[e]*hv[e] + (1.f - zv[e])*ht;
        ho.u[e] = (half_t)hn[e];
      }
      *(f32x4*)&Hout[hidx] = hn;
      *(uint2*)(Out + (size_t)(b*N + n)*256 + j) = ho.qq;
    }
  }
}

// ---------------- readout ----------------
__global__ __launch_bounds__(256) void readout_k(const float* __restrict__ H, const float* __restrict__ W_ro,
                                                 const float* __restrict__ b_ro, const float* __restrict__ W_ag,
                                                 const float* __restrict__ b_ag, float* __restrict__ out) {
  __shared__ float red[256];
  __shared__ float o1[NN];
  int b = blockIdx.x, tid = threadIdx.x;
  float wro = W_ro[tid];
  for (int n = 0; n < NN; ++n) {
    red[tid] = H[((size_t)b*NN + n)*256 + tid] * wro;
    __syncthreads();
    for (int s = 128; s > 0; s >>= 1) { if (tid < s) red[tid] += red[tid+s]; __syncthreads(); }
    if (tid == 0) o1[n] = red[0] + b_ro[0];
    __syncthreads();
  }
  if (tid < 5) {
    float s = b_ag[tid];
    for (int n = 0; n < NN; ++n) s += o1[n] * W_ag[n*5 + tid];
    out[b*5 + tid] = s;
  }
}

// ---------------- host ----------------
extern "C" void kernel_launch(void* const* d_in, const int* in_sizes, int n_in,
                              void* d_out, int out_size, void* d_ws, size_t ws_size,
                              hipStream_t stream) {
  const float* xdis = (const float*)d_in[0];
  const float* xpre = (const float*)d_in[1];
  const int*   ei_s = (const int*)d_in[2];
  const int*   ei_p = (const int*)d_in[3];
  const float* ew_s = (const float*)d_in[4];
  const float* ew_p = (const float*)d_in[5];
  const float* Wz_s = (const float*)d_in[6];
  const float* bz_s = (const float*)d_in[7];
  const float* Wr_s = (const float*)d_in[8];
  const float* br_s = (const float*)d_in[9];
  const float* Wh_s = (const float*)d_in[10];
  const float* bh_s = (const float*)d_in[11];
  const float* Wz_p = (const float*)d_in[12];
  const float* bz_p = (const float*)d_in[13];
  const float* Wr_p = (const float*)d_in[14];
  const float* br_p = (const float*)d_in[15];
  const float* Wh_p = (const float*)d_in[16];
  const float* bh_p = (const float*)d_in[17];
  const float* W_ro = (const float*)d_in[18];
  const float* b_ro = (const float*)d_in[19];
  const float* W_ag = (const float*)d_in[20];
  const float* b_ag = (const float*)d_in[21];
  float* out = (float*)d_out;
  (void)in_sizes; (void)n_in; (void)out_size; (void)ws_size;

  char* w = (char*)d_ws;
  size_t off = 0;
  auto alloc = [&](size_t bytes) { void* p = w + off; off = (off + bytes + 255) & ~(size_t)255; return p; };

  const size_t rowsXs = (size_t)TCH*NB*NSN, rowsXp = (size_t)TCH*NB*NPN;

  float* Ms_s = (float*)alloc(4*NSN*NSN*sizeof(float));
  float* Ms_p = (float*)alloc(2*NPN*NPN*sizeof(float));
  half_t* WX_s = (half_t*)alloc((size_t)768*KHS*2);
  half_t* WX_p = (half_t*)alloc((size_t)768*KHP*2);
  half_t* WHzr_s = (half_t*)alloc((size_t)2560*256*2);
  half_t* WHh_s  = (half_t*)alloc((size_t)1280*256*2);
  half_t* WHzr_p = (half_t*)alloc((size_t)1536*256*2);
  half_t* WHh_p  = (half_t*)alloc((size_t)768*256*2);
  half_t* XT_s = (half_t*)alloc(rowsXs*KHS*2);
  half_t* XT_p = (half_t*)alloc(rowsXp*KHP*2);
  half_t* Px_s = (half_t*)alloc((size_t)TT*NB*NSN*NPRE*2);
  half_t* Px_p = (half_t*)alloc((size_t)TT*NB*NPN*NPRE*2);
  half_t* Y_s = (half_t*)alloc((size_t)NB*NSN*2560*2);
  half_t* Y_p = (half_t*)alloc((size_t)NB*NPN*1536*2);
  float* H  = (float*)alloc((size_t)NB*NN*256*4);
  float* Z  = (float*)alloc((size_t)NB*NN*256*4);
  half_t* Hf  = (half_t*)alloc((size_t)NB*NN*256*2);
  half_t* gHf = (half_t*)alloc((size_t)NB*NN*256*2);
  half_t* Hf_s = Hf,  * Hf_p = Hf + (size_t)NB*NSN*256;
  half_t* gHf_s = gHf, * gHf_p = gHf + (size_t)NB*NSN*256;

  graph_build<<<1, 64, 0, stream>>>(ei_s, ew_s, ei_p, ew_p, Ms_s, Ms_p);
  prep_w<<<1024, 256, 0, stream>>>(Wz_s, Wr_s, Wh_s, Wz_p, Wr_p, Wh_p,
                                   WX_s, WX_p, WHzr_s, WHh_s, WHzr_p, WHh_p);
  const long nH = (long)NB*NN*256;
  zero_f<<<(nH + 255)/256, 256, 0, stream>>>(H, nH);
  zero_f<<<(nH/2 + 255)/256, 256, 0, stream>>>((float*)Hf, nH/2);

  // ---- precompute Px (TCH=8 -> 3 chunks) ----
  for (int t0 = 0; t0 < TT; t0 += TCH) {
    chebx<<<2*NB*TCH, 256, 0, stream>>>(xdis, xpre, Ms_s, Ms_p, XT_s, XT_p, t0);
    gemm_pre<<<448*6, 512, 0, stream>>>(
        XT_s, WX_s, KHS, 320, 6,
        XT_p, WX_p, KHP,
        Px_s + (size_t)t0*NB*NSN*NPRE, Px_p + (size_t)t0*NB*NPN*NPRE,
        bz_s, br_s, bh_s, bz_p, br_p, bh_p);
  }

  // ---- recurrence: 4 dispatches/step (R8 champion structure) ----
  // Mbig matrices for contract: reuse Ms_s-derived layout built on the fly is avoided;
  // contract_k uses Mb arrays, so build them here from graph_build outputs.
  // (Mbig built below once via a tiny kernel-free trick: they were part of graph_build in R8.)
  // -- Mbig buffers:
  static_assert(true, "");
  float* Mbig_s = (float*)alloc(NSN*100*sizeof(float));
  float* Mbig_p = (float*)alloc(NPN*24*sizeof(float));
  {
    // build Mbig from Ms via a small kernel (same math as R8's graph_build tail)
    struct Local {
      static __device__ void dummy() {}
    };
    // use zero_f-style lambda kernel is not possible; do it with a tiny global below.
  }
  // tiny kernel to build Mbig from Ms
  {
    auto build_mbig = [] __device__ () {};
    (void)build_mbig;
  }
  // Use a dedicated kernel:
  extern __global__ void build_mbig_k(const float*, const float*, float*, float*);
  build_mbig_k<<<1, 256, 0, stream>>>(Ms_s, Ms_p, Mbig_s, Mbig_p);

  for (int t = 0; t < TT; ++t) {
    const half_t* PxS = Px_s + (size_t)t*NB*NSN*NPRE;
    const half_t* PxP = Px_p + (size_t)t*NB*NPN*NPRE;
    gemm_y<<<800 + 192, 512, 0, stream>>>(Hf_s, WHzr_s, Y_s, 2560, 20, 800,
                                          Hf_p, WHzr_p, Y_p, 1536, 12);
    contract_k<0><<<NB*4*2, 256, 0, stream>>>(Y_s, Y_p, PxS, PxP, Mbig_s, Mbig_p,
                                              H, Z, gHf_s, gHf_p, nullptr);
    gemm_y<<<400 + 96, 512, 0, stream>>>(gHf_s, WHh_s, Y_s, 1280, 10, 400,
                                         gHf_p, WHh_p, Y_p, 768, 6);
    contract_k<1><<<NB*2*2, 256, 0, stream>>>(Y_s, Y_p, PxS, PxP, Mbig_s, Mbig_p,
                                              H, Z, Hf_s, Hf_p, H);
  }
  readout_k<<<NB, 256, 0, stream>>>(H, W_ro, b_ro, W_ag, b_ag, out);
}

// ---------------- build Mbig from Ms ----------------
__global__ void build_mbig_k(const float* __restrict__ Ms_s, const float* __restrict__ Ms_p,
                             float* __restrict__ Mbig_s, float* __restrict__ Mbig_p) {
  int tid = threadIdx.x;
  for (int i = tid; i < NSN*NSN*5; i += 256) {
    int n = i / 100, s = i % 100, r = s / 5, tau = s % 5;
    float v;
    if (tau == 0) v = (n == r) ? 1.f : 0.f;
    else v = Ms_s[(tau - 1)*NSN*NSN + n*NSN + r];
    Mbig_s[i] = v;
  }
  for (int i = tid; i < NPN*NPN*3; i += 256) {
    int n = i / 24, s = i % 24, r = s / 3, tau = s % 3;
    float v;
    if (tau == 0) v = (n == r) ? 1.f : 0.f;
    else v = Ms_p[(tau - 1)*NPN*NPN + n*NPN + r];
    Mbig_p[i] = v;
  }
}